// Round 4
// baseline (200.094 us; speedup 1.0000x reference)
//
#include <hip/hip_runtime.h>

// DemandMap: site_type_map (4096x4096 int32, row-major [x][y]) ->
// out [7][2048][2048] fp32 = bin_area(4.0) - per-type demand.
//
// Geometry collapse (verified R1, absmax=0.0): binW=binH=2, integer site
// coords, node sizes in [0,1) => each site overlaps exactly its home bin
// (x/2, y/2) with area ((x+nw)-x) * ((y+nh)-y) in fp32 (reference rounding).
// Maps 0..4 replicate type-1 demand, map 5 = type 2, map 6 = type 3.
//
// R4: 8 y-bins/thread, arranged so every store instruction is a dense
// 1KB contiguous run across the wave (lane l -> float4 idx i*512+128k+l,
// second group at +64). Nontemporal ONLY on stores (dense, full-line).
// Loads are normal cached (50%-dense per instr; L2 merges, 1 fetch/line).

constexpr int NBX  = 2048;
constexpr int NBY  = 2048;
constexpr int H    = 4096;             // site map height (y extent)
constexpr int MAPQ = NBX * NBY / 4;    // 16B-vector elements per output map

typedef int   vint4   __attribute__((ext_vector_type(4)));
typedef float vfloat4 __attribute__((ext_vector_type(4)));

__global__ __launch_bounds__(256) void demand_map_kernel(
    const int*   __restrict__ st,
    const float* __restrict__ nsx,
    const float* __restrict__ nsy,
    vfloat4*     __restrict__ out)
{
    const int tid = blockIdx.x * 256 + threadIdx.x;
    const int i   = tid >> 8;          // bin-x index (0..2047)
    const int r   = tid & 255;         // thread within this bin-x row
    const int k   = r >> 6;            // wave within row (0..3)
    const int l   = r & 63;            // lane
    const int q1  = 128 * k + l;       // first float4-column (0..511)
    const int q2  = q1 + 64;           // second float4-column

    const float nwx1 = nsx[1], nwx2 = nsx[2], nwx3 = nsx[3];
    const float nwy1 = nsy[1], nwy2 = nsy[2], nwy3 = nsy[3];

    const int   row0 = i * 2;
    const float xf0  = (float)row0;
    const float xf1  = (float)(row0 + 1);

    // per-row, per-type wx = (x + nw) - x  (reference fp32 rounding)
    const float wx0t1 = (xf0 + nwx1) - xf0, wx0t2 = (xf0 + nwx2) - xf0, wx0t3 = (xf0 + nwx3) - xf0;
    const float wx1t1 = (xf1 + nwx1) - xf1, wx1t2 = (xf1 + nwx2) - xf1, wx1t3 = (xf1 + nwx3) - xf1;

    // 8 independent 16B loads (deep MLP), normal cached.
    const vint4* base = reinterpret_cast<const vint4*>(st);  // row stride 1024
    const size_t r0b = (size_t)row0 * 1024;
    const size_t r1b = r0b + 1024;
    const vint4 a0 = base[r0b + 2 * q1];
    const vint4 a1 = base[r0b + 2 * q1 + 1];
    const vint4 b0 = base[r0b + 2 * q2];
    const vint4 b1 = base[r0b + 2 * q2 + 1];
    const vint4 c0 = base[r1b + 2 * q1];
    const vint4 c1 = base[r1b + 2 * q1 + 1];
    const vint4 d0 = base[r1b + 2 * q2];
    const vint4 d1 = base[r1b + 2 * q2 + 1];

    auto compute = [&](vint4 r0a, vint4 r0bv, vint4 r1a, vint4 r1bv, int ybase,
                       vfloat4& o0, vfloat4& o5, vfloat4& o6) {
        const int t0[8] = { r0a.x, r0a.y, r0a.z, r0a.w, r0bv.x, r0bv.y, r0bv.z, r0bv.w };
        const int t1[8] = { r1a.x, r1a.y, r1a.z, r1a.w, r1bv.x, r1bv.y, r1bv.z, r1bv.w };
        float v0[4], v5[4], v6[4];
        #pragma unroll
        for (int b = 0; b < 4; ++b) {
            float acc1 = 0.f, acc2 = 0.f, acc3 = 0.f;
            #pragma unroll
            for (int c = 0; c < 2; ++c) {
                const float yf = (float)(ybase + 2 * b + c);
                {   // row 0 site
                    const int t = t0[2 * b + c];
                    const float nh = (t == 1) ? nwy1 : ((t == 2) ? nwy2 : nwy3);
                    const float wx = (t == 1) ? wx0t1 : ((t == 2) ? wx0t2 : wx0t3);
                    const float a  = wx * ((yf + nh) - yf);
                    acc1 += (t == 1) ? a : 0.f;
                    acc2 += (t == 2) ? a : 0.f;
                    acc3 += (t == 3) ? a : 0.f;
                }
                {   // row 1 site
                    const int t = t1[2 * b + c];
                    const float nh = (t == 1) ? nwy1 : ((t == 2) ? nwy2 : nwy3);
                    const float wx = (t == 1) ? wx1t1 : ((t == 2) ? wx1t2 : wx1t3);
                    const float a  = wx * ((yf + nh) - yf);
                    acc1 += (t == 1) ? a : 0.f;
                    acc2 += (t == 2) ? a : 0.f;
                    acc3 += (t == 3) ? a : 0.f;
                }
            }
            v0[b] = 4.0f - acc1;
            v5[b] = 4.0f - acc2;
            v6[b] = 4.0f - acc3;
        }
        o0 = (vfloat4){ v0[0], v0[1], v0[2], v0[3] };
        o5 = (vfloat4){ v5[0], v5[1], v5[2], v5[3] };
        o6 = (vfloat4){ v6[0], v6[1], v6[2], v6[3] };
    };

    vfloat4 A0, A5, A6, B0, B5, B6;
    compute(a0, a1, c0, c1, 8 * q1, A0, A5, A6);
    compute(b0, b1, d0, d1, 8 * q2, B0, B5, B6);

    // Dense stores: lanes l=0..63 write consecutive float4 -> 1KB/instr.
    const size_t o1 = (size_t)i * (NBY / 4) + q1;
    const size_t o2 = o1 + 64;
    #pragma unroll
    for (int m = 0; m < 5; ++m) {                 // maps 0..4 alias c0
        __builtin_nontemporal_store(A0, out + (size_t)m * MAPQ + o1);
        __builtin_nontemporal_store(B0, out + (size_t)m * MAPQ + o2);
    }
    __builtin_nontemporal_store(A5, out + (size_t)5 * MAPQ + o1);
    __builtin_nontemporal_store(B5, out + (size_t)5 * MAPQ + o2);
    __builtin_nontemporal_store(A6, out + (size_t)6 * MAPQ + o1);
    __builtin_nontemporal_store(B6, out + (size_t)6 * MAPQ + o2);
}

extern "C" void kernel_launch(void* const* d_in, const int* in_sizes, int n_in,
                              void* d_out, int out_size, void* d_ws, size_t ws_size,
                              hipStream_t stream) {
    const int*   st  = (const int*)d_in[0];    // site_type_map, 4096*4096 int32
    const float* nsx = (const float*)d_in[1];  // node_size_x, 4 floats
    const float* nsy = (const float*)d_in[2];  // node_size_y, 4 floats
    vfloat4*     out = (vfloat4*)d_out;        // 7*2048*2048 fp32

    const int total_threads = NBX * (NBY / 8); // 2048 * 256 = 524,288
    const int block = 256;
    const int grid  = total_threads / block;   // 2048

    demand_map_kernel<<<grid, block, 0, stream>>>(st, nsx, nsy, out);
}

// Round 5
// 168.779 us; speedup vs baseline: 1.1855x; 1.1855x over previous
//
#include <hip/hip_runtime.h>

// DemandMap: site_type_map (4096x4096 int32, row-major [x][y]) ->
// out [7][2048][2048] fp32 = bin_area(4.0) - per-type demand.
//
// Geometry collapse (verified R1, absmax=0.0): binW=binH=2, integer site
// coords, node sizes in [0,1) => each site overlaps exactly its home bin
// (x/2, y/2) with area ((x+nw)-x) * ((y+nh)-y) in fp32 (reference rounding).
// Maps 0..4 replicate type-1 demand, map 5 = type 2, map 6 = type 3.
//
// R5: back to R1 mapping (1M threads, 4 y-bins/thread, dense stores), but
// with ZERO per-thread arrays/lambdas (R4 showed the compiler demoted them
// to LDS: LDS_Block_Size=18432, 1.74M bank conflicts) and NO nontemporal
// ops (R3/R4 both regressed with nt; plain cached path hits 6.9 TB/s in
// the harness fill).

constexpr int NBX  = 2048;
constexpr int NBY  = 2048;
constexpr int H    = 4096;             // site map height (y extent)
constexpr int MAPQ = NBX * NBY / 4;    // float4 elements per output map

__device__ __forceinline__ void site(int t, float yf,
                                     float wxt1, float wxt2, float wxt3,
                                     float nwy1, float nwy2, float nwy3,
                                     float& a1, float& a2, float& a3)
{
    const float nh = (t == 1) ? nwy1 : ((t == 2) ? nwy2 : nwy3);
    const float wx = (t == 1) ? wxt1 : ((t == 2) ? wxt2 : wxt3);
    const float a  = wx * ((yf + nh) - yf);   // reference fp32 rounding
    a1 += (t == 1) ? a : 0.f;
    a2 += (t == 2) ? a : 0.f;
    a3 += (t == 3) ? a : 0.f;
}

__global__ __launch_bounds__(256) void demand_map_kernel(
    const int*   __restrict__ st,
    const float* __restrict__ nsx,
    const float* __restrict__ nsy,
    float4*      __restrict__ out)
{
    const int tid = blockIdx.x * 256 + threadIdx.x;
    const int i   = tid >> 9;          // bin-x index (0..2047)
    const int jg  = tid & 511;         // group of 4 bins along y (0..511)

    const float nwx1 = nsx[1], nwx2 = nsx[2], nwx3 = nsx[3];
    const float nwy1 = nsy[1], nwy2 = nsy[2], nwy3 = nsy[3];

    const int   row0 = i * 2;
    const float xf0  = (float)row0;
    const float xf1  = (float)(row0 + 1);

    // per-row, per-type wx = (x + nw) - x  (reference fp32 rounding)
    const float wx01 = (xf0 + nwx1) - xf0, wx02 = (xf0 + nwx2) - xf0, wx03 = (xf0 + nwx3) - xf0;
    const float wx11 = (xf1 + nwx1) - xf1, wx12 = (xf1 + nwx2) - xf1, wx13 = (xf1 + nwx3) - xf1;

    // 4 independent 16B cached loads; lanes consecutive -> lines fully
    // covered across the wave, one fetch per line.
    const int4* p0 = reinterpret_cast<const int4*>(st + (size_t)row0 * H + 8 * jg);
    const int4* p1 = reinterpret_cast<const int4*>(st + ((size_t)row0 + 1) * H + 8 * jg);
    const int4 r0a = p0[0];
    const int4 r0b = p0[1];
    const int4 r1a = p1[0];
    const int4 r1b = p1[1];

    const float y0 = (float)(jg * 8);
    const float y1 = y0 + 1.f, y2 = y0 + 2.f, y3 = y0 + 3.f;
    const float y4 = y0 + 4.f, y5 = y0 + 5.f, y6 = y0 + 6.f, y7 = y0 + 7.f;

    float4 V0, V5, V6;
    float a1, a2, a3;

    // bin b=0: sites (row0,y0),(row0,y1),(row1,y0),(row1,y1)
    a1 = 0.f; a2 = 0.f; a3 = 0.f;
    site(r0a.x, y0, wx01, wx02, wx03, nwy1, nwy2, nwy3, a1, a2, a3);
    site(r0a.y, y1, wx01, wx02, wx03, nwy1, nwy2, nwy3, a1, a2, a3);
    site(r1a.x, y0, wx11, wx12, wx13, nwy1, nwy2, nwy3, a1, a2, a3);
    site(r1a.y, y1, wx11, wx12, wx13, nwy1, nwy2, nwy3, a1, a2, a3);
    V0.x = 4.0f - a1; V5.x = 4.0f - a2; V6.x = 4.0f - a3;

    // bin b=1
    a1 = 0.f; a2 = 0.f; a3 = 0.f;
    site(r0a.z, y2, wx01, wx02, wx03, nwy1, nwy2, nwy3, a1, a2, a3);
    site(r0a.w, y3, wx01, wx02, wx03, nwy1, nwy2, nwy3, a1, a2, a3);
    site(r1a.z, y2, wx11, wx12, wx13, nwy1, nwy2, nwy3, a1, a2, a3);
    site(r1a.w, y3, wx11, wx12, wx13, nwy1, nwy2, nwy3, a1, a2, a3);
    V0.y = 4.0f - a1; V5.y = 4.0f - a2; V6.y = 4.0f - a3;

    // bin b=2
    a1 = 0.f; a2 = 0.f; a3 = 0.f;
    site(r0b.x, y4, wx01, wx02, wx03, nwy1, nwy2, nwy3, a1, a2, a3);
    site(r0b.y, y5, wx01, wx02, wx03, nwy1, nwy2, nwy3, a1, a2, a3);
    site(r1b.x, y4, wx11, wx12, wx13, nwy1, nwy2, nwy3, a1, a2, a3);
    site(r1b.y, y5, wx11, wx12, wx13, nwy1, nwy2, nwy3, a1, a2, a3);
    V0.z = 4.0f - a1; V5.z = 4.0f - a2; V6.z = 4.0f - a3;

    // bin b=3
    a1 = 0.f; a2 = 0.f; a3 = 0.f;
    site(r0b.z, y6, wx01, wx02, wx03, nwy1, nwy2, nwy3, a1, a2, a3);
    site(r0b.w, y7, wx01, wx02, wx03, nwy1, nwy2, nwy3, a1, a2, a3);
    site(r1b.z, y6, wx11, wx12, wx13, nwy1, nwy2, nwy3, a1, a2, a3);
    site(r1b.w, y7, wx11, wx12, wx13, nwy1, nwy2, nwy3, a1, a2, a3);
    V0.w = 4.0f - a1; V5.w = 4.0f - a2; V6.w = 4.0f - a3;

    // Dense stores: lanes consecutive float4 -> full 1KB per wave per instr.
    const size_t obase = (size_t)i * (NBY / 4) + jg;
    out[               obase] = V0;    // map 0
    out[    MAPQ     + obase] = V0;    // map 1
    out[2 * (size_t)MAPQ + obase] = V0;    // map 2
    out[3 * (size_t)MAPQ + obase] = V0;    // map 3
    out[4 * (size_t)MAPQ + obase] = V0;    // map 4
    out[5 * (size_t)MAPQ + obase] = V5;    // map 5
    out[6 * (size_t)MAPQ + obase] = V6;    // map 6
}

extern "C" void kernel_launch(void* const* d_in, const int* in_sizes, int n_in,
                              void* d_out, int out_size, void* d_ws, size_t ws_size,
                              hipStream_t stream) {
    const int*   st  = (const int*)d_in[0];    // site_type_map, 4096*4096 int32
    const float* nsx = (const float*)d_in[1];  // node_size_x, 4 floats
    const float* nsy = (const float*)d_in[2];  // node_size_y, 4 floats
    float4*      out = (float4*)d_out;         // 7*2048*2048 fp32

    const int total_threads = NBX * (NBY / 4); // 2048 * 512 = 1,048,576
    const int block = 256;
    const int grid  = total_threads / block;   // 4096

    demand_map_kernel<<<grid, block, 0, stream>>>(st, nsx, nsy, out);
}